// Round 1
// baseline (2566.458 us; speedup 1.0000x reference)
//
#include <hip/hip_runtime.h>
#include <math.h>

#define B_ 2
#define T_ 2048
#define C_ 2048
#define H_ 16
#define HKV_ 4
#define D_ 128
#define G_ (H_ / HKV_)

// ---------------------------------------------------------------------------
// Fused QKV projection GEMM: X[4096,2048] @ {Wq|Wk|Wv} -> q/k/v in
// [B, heads, T, D] layout. BM=BN=128, BK=8, 256 threads, 8x8 micro-tile.
// ---------------------------------------------------------------------------
#define BM 128
#define BN 128
#define BK 8

__global__ __launch_bounds__(256, 2)
void qkv_gemm(const float* __restrict__ X,
              const float* __restrict__ Wq,
              const float* __restrict__ Wk,
              const float* __restrict__ Wv,
              float* __restrict__ qbuf,
              float* __restrict__ kbuf,
              float* __restrict__ vbuf)
{
    __shared__ float As[BK][BM + 4];
    __shared__ float Bs[BK][BN + 4];

    const int tid = threadIdx.x;
    const int bx = blockIdx.x;   // N blocks: 3072/128 = 24
    const int by = blockIdx.y;   // M blocks: 4096/128 = 32

    const int n0 = bx * BN;
    const float* W; float* outbuf; int NH; int nc;
    if (n0 < H_ * D_)                  { W = Wq; outbuf = qbuf; NH = H_;   nc = n0; }
    else if (n0 < (H_ + HKV_) * D_)    { W = Wk; outbuf = kbuf; NH = HKV_; nc = n0 - H_ * D_; }
    else                               { W = Wv; outbuf = vbuf; NH = HKV_; nc = n0 - (H_ + HKV_) * D_; }
    const int Nw = NH * D_;  // 2048 or 512

    const int m0 = by * BM;
    const int tx = tid & 15;
    const int ty = tid >> 4;

    float acc[8][8];
    #pragma unroll
    for (int i = 0; i < 8; ++i)
        #pragma unroll
        for (int j = 0; j < 8; ++j) acc[i][j] = 0.f;

    const int arow = tid >> 1;          // 0..127
    const int akq  = (tid & 1) * 4;     // 0 or 4
    const int brow = tid >> 5;          // 0..7
    const int bcol = (tid & 31) * 4;    // 0..124

    for (int k0 = 0; k0 < C_; k0 += BK) {
        float4 av = *(const float4*)&X[(size_t)(m0 + arow) * C_ + k0 + akq];
        float4 bv = *(const float4*)&W[(size_t)(k0 + brow) * Nw + nc + bcol];

        __syncthreads();   // previous tile's reads complete
        As[akq + 0][arow] = av.x;
        As[akq + 1][arow] = av.y;
        As[akq + 2][arow] = av.z;
        As[akq + 3][arow] = av.w;
        *(float4*)&Bs[brow][bcol] = bv;
        __syncthreads();

        #pragma unroll
        for (int k = 0; k < BK; ++k) {
            float4 a0 = *(const float4*)&As[k][ty * 8];
            float4 a1 = *(const float4*)&As[k][ty * 8 + 4];
            float4 b0 = *(const float4*)&Bs[k][tx * 8];
            float4 b1 = *(const float4*)&Bs[k][tx * 8 + 4];
            float a_[8] = {a0.x, a0.y, a0.z, a0.w, a1.x, a1.y, a1.z, a1.w};
            float b_[8] = {b0.x, b0.y, b0.z, b0.w, b1.x, b1.y, b1.z, b1.w};
            #pragma unroll
            for (int i = 0; i < 8; ++i)
                #pragma unroll
                for (int j = 0; j < 8; ++j)
                    acc[i][j] = fmaf(a_[i], b_[j], acc[i][j]);
        }
    }

    // epilogue -> [B, NH, T, D]; BN==D so one head per block; BM divides T.
    const int b  = m0 / T_;
    const int t0 = m0 % T_;
    const int h0 = nc / D_;
    float* outp = outbuf + (size_t)(b * NH + h0) * T_ * D_;
    #pragma unroll
    for (int i = 0; i < 8; ++i) {
        const int t = t0 + ty * 8 + i;
        float4 o0 = {acc[i][0], acc[i][1], acc[i][2], acc[i][3]};
        float4 o1 = {acc[i][4], acc[i][5], acc[i][6], acc[i][7]};
        *(float4*)&outp[(size_t)t * D_ + tx * 8]     = o0;
        *(float4*)&outp[(size_t)t * D_ + tx * 8 + 4] = o1;
    }
}

// ---------------------------------------------------------------------------
// Output projection GEMM: abuf[4096,2048] @ Wo[2048,2048] -> out[4096,2048]
// ---------------------------------------------------------------------------
__global__ __launch_bounds__(256, 2)
void out_gemm(const float* __restrict__ A,
              const float* __restrict__ W,
              float* __restrict__ Cout)
{
    __shared__ float As[BK][BM + 4];
    __shared__ float Bs[BK][BN + 4];

    const int tid = threadIdx.x;
    const int n0 = blockIdx.x * BN;
    const int m0 = blockIdx.y * BM;
    const int tx = tid & 15;
    const int ty = tid >> 4;

    float acc[8][8];
    #pragma unroll
    for (int i = 0; i < 8; ++i)
        #pragma unroll
        for (int j = 0; j < 8; ++j) acc[i][j] = 0.f;

    const int arow = tid >> 1;
    const int akq  = (tid & 1) * 4;
    const int brow = tid >> 5;
    const int bcol = (tid & 31) * 4;

    for (int k0 = 0; k0 < C_; k0 += BK) {
        float4 av = *(const float4*)&A[(size_t)(m0 + arow) * C_ + k0 + akq];
        float4 bv = *(const float4*)&W[(size_t)(k0 + brow) * C_ + n0 + bcol];

        __syncthreads();
        As[akq + 0][arow] = av.x;
        As[akq + 1][arow] = av.y;
        As[akq + 2][arow] = av.z;
        As[akq + 3][arow] = av.w;
        *(float4*)&Bs[brow][bcol] = bv;
        __syncthreads();

        #pragma unroll
        for (int k = 0; k < BK; ++k) {
            float4 a0 = *(const float4*)&As[k][ty * 8];
            float4 a1 = *(const float4*)&As[k][ty * 8 + 4];
            float4 b0 = *(const float4*)&Bs[k][tx * 8];
            float4 b1 = *(const float4*)&Bs[k][tx * 8 + 4];
            float a_[8] = {a0.x, a0.y, a0.z, a0.w, a1.x, a1.y, a1.z, a1.w};
            float b_[8] = {b0.x, b0.y, b0.z, b0.w, b1.x, b1.y, b1.z, b1.w};
            #pragma unroll
            for (int i = 0; i < 8; ++i)
                #pragma unroll
                for (int j = 0; j < 8; ++j)
                    acc[i][j] = fmaf(a_[i], b_[j], acc[i][j]);
        }
    }

    #pragma unroll
    for (int i = 0; i < 8; ++i) {
        float4 o0 = {acc[i][0], acc[i][1], acc[i][2], acc[i][3]};
        float4 o1 = {acc[i][4], acc[i][5], acc[i][6], acc[i][7]};
        *(float4*)&Cout[(size_t)(m0 + ty * 8 + i) * C_ + n0 + tx * 8]     = o0;
        *(float4*)&Cout[(size_t)(m0 + ty * 8 + i) * C_ + n0 + tx * 8 + 4] = o1;
    }
}

// ---------------------------------------------------------------------------
// RoPE in-place on [B, NH, T, D]; one thread per (row, pair j<64).
// out[d]    = x[d]*cos - x[d+64]*sin
// out[d+64] = x[d+64]*cos + x[d]*sin,   freq = t * theta^(-j/64)
// ---------------------------------------------------------------------------
__global__ void rope_kernel(float* __restrict__ buf)
{
    const int idx = blockIdx.x * blockDim.x + threadIdx.x;
    const int j   = idx & 63;
    const int row = idx >> 6;          // (b*NH + h)*T + t
    const int t   = row & (T_ - 1);    // T_ = 2048 power of two

    const float LOG_THETA = 9.210340371976184f;  // ln(10000)
    const float freq = (float)t * expf(-(float)j * (LOG_THETA / 64.0f));
    const float cc = cosf(freq);
    const float ss = sinf(freq);

    const size_t base = (size_t)row * D_ + j;
    const float x1 = buf[base];
    const float x2 = buf[base + 64];
    buf[base]      = x1 * cc - x2 * ss;
    buf[base + 64] = x2 * cc + x1 * ss;
}

// ---------------------------------------------------------------------------
// Flash attention (fp32, causal, GQA). Block = 128 threads handles QT=16 query
// rows of one (b,h); iterates KT=32 key rows per tile with online softmax.
// Thread (qr = tid/8, c = tid%8): owns S cols kc=j*8+c (j<4) and O cols
// d4 = jj*8+c (jj<4, 4 floats each).
// ---------------------------------------------------------------------------
#define QT 16
#define KT 32

__global__ __launch_bounds__(128)
void flash_attn(const float* __restrict__ qbuf,
                const float* __restrict__ kbuf,
                const float* __restrict__ vbuf,
                float* __restrict__ abuf)
{
    __shared__ float Qs[QT][D_ + 4];
    __shared__ float Ks[KT][D_ + 4];
    __shared__ float Vs[KT][D_ + 4];
    __shared__ float Ps[QT][KT + 1];

    const int tid   = threadIdx.x;
    const int qtile = blockIdx.x;          // T/QT = 128
    const int bh    = blockIdx.y;          // B*H = 32
    const int b   = bh / H_;
    const int h   = bh % H_;
    const int kvh = h / G_;

    const int qt0 = qtile * QT;
    const float* qg = qbuf + ((size_t)(b * H_ + h) * T_ + qt0) * D_;
    const float* kg = kbuf + (size_t)(b * HKV_ + kvh) * T_ * D_;
    const float* vg = vbuf + (size_t)(b * HKV_ + kvh) * T_ * D_;

    const int qr   = tid >> 3;   // 0..15
    const int c    = tid & 7;    // 0..7
    const int qr_g = qt0 + qr;

    // load Q tile (16x128): 512 float4, 4 per thread
    #pragma unroll
    for (int i = 0; i < 4; ++i) {
        const int idx = i * 128 + tid;
        const int r = idx >> 5, c4 = (idx & 31) << 2;
        *(float4*)&Qs[r][c4] = *(const float4*)&qg[(size_t)r * D_ + c4];
    }

    float m = -INFINITY, l = 0.f;
    float acc[4][4];
    #pragma unroll
    for (int jj = 0; jj < 4; ++jj)
        #pragma unroll
        for (int ii = 0; ii < 4; ++ii) acc[jj][ii] = 0.f;

    const float scale = 0.08838834764831845f;  // 1/sqrt(128)

    for (int k0 = 0; k0 <= qt0 + QT - 1; k0 += KT) {
        __syncthreads();   // previous tile's PV reads complete
        // load K,V tiles (32x128 each): 1024 float4 each, 8 per thread
        #pragma unroll
        for (int i = 0; i < 8; ++i) {
            const int idx = i * 128 + tid;
            const int r = idx >> 5, c4 = (idx & 31) << 2;
            *(float4*)&Ks[r][c4] = *(const float4*)&kg[(size_t)(k0 + r) * D_ + c4];
            *(float4*)&Vs[r][c4] = *(const float4*)&vg[(size_t)(k0 + r) * D_ + c4];
        }
        __syncthreads();

        // S = Q K^T for this thread's 4 columns
        float s[4] = {0.f, 0.f, 0.f, 0.f};
        #pragma unroll 4
        for (int d4 = 0; d4 < 32; ++d4) {
            const float4 q4 = *(const float4*)&Qs[qr][d4 << 2];
            #pragma unroll
            for (int j = 0; j < 4; ++j) {
                const float4 k4 = *(const float4*)&Ks[j * 8 + c][d4 << 2];
                s[j] += q4.x * k4.x + q4.y * k4.y + q4.z * k4.z + q4.w * k4.w;
            }
        }
        float pmax = -INFINITY;
        #pragma unroll
        for (int j = 0; j < 4; ++j) {
            const int kc_g = k0 + j * 8 + c;
            s[j] = (kc_g <= qr_g) ? s[j] * scale : -INFINITY;
            pmax = fmaxf(pmax, s[j]);
        }
        #pragma unroll
        for (int off = 1; off < 8; off <<= 1)
            pmax = fmaxf(pmax, __shfl_xor(pmax, off, 8));

        const float newm = fmaxf(m, pmax);
        const float corr = __expf(m - newm);   // first iter: exp(-inf)=0
        float psum = 0.f;
        #pragma unroll
        for (int j = 0; j < 4; ++j) {
            const float p = __expf(s[j] - newm);
            Ps[qr][j * 8 + c] = p;
            psum += p;
        }
        #pragma unroll
        for (int off = 1; off < 8; off <<= 1)
            psum += __shfl_xor(psum, off, 8);
        l = l * corr + psum;
        m = newm;
        #pragma unroll
        for (int jj = 0; jj < 4; ++jj)
            #pragma unroll
            for (int ii = 0; ii < 4; ++ii) acc[jj][ii] *= corr;
        __syncthreads();   // Ps visible

        // O += P V
        for (int kc = 0; kc < KT; ++kc) {
            const float p = Ps[qr][kc];
            #pragma unroll
            for (int jj = 0; jj < 4; ++jj) {
                const float4 v4 = *(const float4*)&Vs[kc][(jj * 8 + c) << 2];
                acc[jj][0] += p * v4.x;
                acc[jj][1] += p * v4.y;
                acc[jj][2] += p * v4.z;
                acc[jj][3] += p * v4.w;
            }
        }
    }

    const float inv_l = 1.f / l;
    float* og = abuf + ((size_t)(b * T_) + qr_g) * (H_ * D_) + h * D_;
    #pragma unroll
    for (int jj = 0; jj < 4; ++jj) {
        float4 o;
        o.x = acc[jj][0] * inv_l;
        o.y = acc[jj][1] * inv_l;
        o.z = acc[jj][2] * inv_l;
        o.w = acc[jj][3] * inv_l;
        *(float4*)&og[(jj * 8 + c) << 2] = o;
    }
}

// ---------------------------------------------------------------------------
extern "C" void kernel_launch(void* const* d_in, const int* in_sizes, int n_in,
                              void* d_out, int out_size, void* d_ws, size_t ws_size,
                              hipStream_t stream)
{
    (void)in_sizes; (void)n_in; (void)out_size; (void)ws_size;
    const float* x  = (const float*)d_in[0];
    const float* Wq = (const float*)d_in[1];
    const float* Wk = (const float*)d_in[2];
    const float* Wv = (const float*)d_in[3];
    const float* Wo = (const float*)d_in[4];
    // d_in[5] = causal mask, handled analytically.
    float* out = (float*)d_out;

    float* ws   = (float*)d_ws;
    float* qbuf = ws;                                       // B*H*T*D   = 8388608
    float* kbuf = qbuf + (size_t)B_ * H_   * T_ * D_;       // B*HKV*T*D = 2097152
    float* vbuf = kbuf + (size_t)B_ * HKV_ * T_ * D_;
    float* abuf = vbuf + (size_t)B_ * HKV_ * T_ * D_;       // B*T*H*D   = 8388608

    // 1) fused QKV projection
    dim3 g1((H_ + 2 * HKV_) * D_ / BN, (B_ * T_) / BM);     // 24 x 32
    hipLaunchKernelGGL(qkv_gemm, g1, dim3(256), 0, stream,
                       x, Wq, Wk, Wv, qbuf, kbuf, vbuf);

    // 2) RoPE on q and k
    {
        const int nq = B_ * H_ * T_ * 64;
        hipLaunchKernelGGL(rope_kernel, dim3(nq / 256), dim3(256), 0, stream, qbuf);
        const int nk = B_ * HKV_ * T_ * 64;
        hipLaunchKernelGGL(rope_kernel, dim3(nk / 256), dim3(256), 0, stream, kbuf);
    }

    // 3) flash attention -> abuf [B, T, H*D]
    hipLaunchKernelGGL(flash_attn, dim3(T_ / QT, B_ * H_), dim3(128), 0, stream,
                       qbuf, kbuf, vbuf, abuf);

    // 4) output projection
    dim3 g4(C_ / BN, (B_ * T_) / BM);                       // 16 x 32
    hipLaunchKernelGGL(out_gemm, g4, dim3(256), 0, stream, abuf, Wo, out);
}

// Round 3
// 1419.846 us; speedup vs baseline: 1.8076x; 1.8076x over previous
//
#include <hip/hip_runtime.h>
#include <math.h>

#define B_ 2
#define T_ 2048
#define C_ 2048
#define H_ 16
#define HKV_ 4
#define D_ 128
#define G_ (H_ / HKV_)

typedef float f32x4 __attribute__((ext_vector_type(4)));
typedef __bf16 bf16x8 __attribute__((ext_vector_type(8)));

static __device__ __forceinline__ f32x4 mfma16(bf16x8 a, bf16x8 b, f32x4 c) {
    return __builtin_amdgcn_mfma_f32_16x16x32_bf16(a, b, c, 0, 0, 0);
}

// ---------------------------------------------------------------------------
// Fused QKV projection GEMM (fp32 math, bf16 output): X[4096,2048] @ {Wq|Wk|Wv}
// -> q/k/v in [B, heads, T, D] bf16. BM=BN=128, BK=8, 256 thr, 8x8 micro-tile.
// ---------------------------------------------------------------------------
#define BM 128
#define BN 128
#define BK 8

__global__ __launch_bounds__(256, 2)
void qkv_gemm(const float* __restrict__ X,
              const float* __restrict__ Wq,
              const float* __restrict__ Wk,
              const float* __restrict__ Wv,
              __bf16* __restrict__ qbuf,
              __bf16* __restrict__ kbuf,
              __bf16* __restrict__ vbuf)
{
    __shared__ float As[BK][BM + 4];
    __shared__ float Bs[BK][BN + 4];

    const int tid = threadIdx.x;
    const int n0 = blockIdx.x * BN;

    const float* W; __bf16* outbuf; int NH; int nc;
    if (n0 < H_ * D_)                  { W = Wq; outbuf = qbuf; NH = H_;   nc = n0; }
    else if (n0 < (H_ + HKV_) * D_)    { W = Wk; outbuf = kbuf; NH = HKV_; nc = n0 - H_ * D_; }
    else                               { W = Wv; outbuf = vbuf; NH = HKV_; nc = n0 - (H_ + HKV_) * D_; }
    const int Nw = NH * D_;

    const int m0 = blockIdx.y * BM;
    const int tx = tid & 15;
    const int ty = tid >> 4;

    float acc[8][8];
    #pragma unroll
    for (int i = 0; i < 8; ++i)
        #pragma unroll
        for (int j = 0; j < 8; ++j) acc[i][j] = 0.f;

    const int arow = tid >> 1;
    const int akq  = (tid & 1) * 4;
    const int brow = tid >> 5;
    const int bcol = (tid & 31) * 4;

    for (int k0 = 0; k0 < C_; k0 += BK) {
        float4 av = *(const float4*)&X[(size_t)(m0 + arow) * C_ + k0 + akq];
        float4 bv = *(const float4*)&W[(size_t)(k0 + brow) * Nw + nc + bcol];

        __syncthreads();
        As[akq + 0][arow] = av.x;
        As[akq + 1][arow] = av.y;
        As[akq + 2][arow] = av.z;
        As[akq + 3][arow] = av.w;
        *(float4*)&Bs[brow][bcol] = bv;
        __syncthreads();

        #pragma unroll
        for (int k = 0; k < BK; ++k) {
            float4 a0 = *(const float4*)&As[k][ty * 8];
            float4 a1 = *(const float4*)&As[k][ty * 8 + 4];
            float4 b0 = *(const float4*)&Bs[k][tx * 8];
            float4 b1 = *(const float4*)&Bs[k][tx * 8 + 4];
            float a_[8] = {a0.x, a0.y, a0.z, a0.w, a1.x, a1.y, a1.z, a1.w};
            float b_[8] = {b0.x, b0.y, b0.z, b0.w, b1.x, b1.y, b1.z, b1.w};
            #pragma unroll
            for (int i = 0; i < 8; ++i)
                #pragma unroll
                for (int j = 0; j < 8; ++j)
                    acc[i][j] = fmaf(a_[i], b_[j], acc[i][j]);
        }
    }

    const int b  = m0 / T_;
    const int t0 = m0 % T_;
    const int h0 = nc / D_;
    __bf16* outp = outbuf + (size_t)(b * NH + h0) * T_ * D_;
    #pragma unroll
    for (int i = 0; i < 8; ++i) {
        const int t = t0 + ty * 8 + i;
        bf16x8 o;
        #pragma unroll
        for (int j = 0; j < 8; ++j) o[j] = (__bf16)acc[i][j];
        *(bf16x8*)&outp[(size_t)t * D_ + tx * 8] = o;
    }
}

// ---------------------------------------------------------------------------
// Output projection GEMM (fp32): abuf[4096,2048] @ Wo[2048,2048] -> out
// ---------------------------------------------------------------------------
__global__ __launch_bounds__(256, 2)
void out_gemm(const float* __restrict__ A,
              const float* __restrict__ W,
              float* __restrict__ Cout)
{
    __shared__ float As[BK][BM + 4];
    __shared__ float Bs[BK][BN + 4];

    const int tid = threadIdx.x;
    const int n0 = blockIdx.x * BN;
    const int m0 = blockIdx.y * BM;
    const int tx = tid & 15;
    const int ty = tid >> 4;

    float acc[8][8];
    #pragma unroll
    for (int i = 0; i < 8; ++i)
        #pragma unroll
        for (int j = 0; j < 8; ++j) acc[i][j] = 0.f;

    const int arow = tid >> 1;
    const int akq  = (tid & 1) * 4;
    const int brow = tid >> 5;
    const int bcol = (tid & 31) * 4;

    for (int k0 = 0; k0 < C_; k0 += BK) {
        float4 av = *(const float4*)&A[(size_t)(m0 + arow) * C_ + k0 + akq];
        float4 bv = *(const float4*)&W[(size_t)(k0 + brow) * C_ + n0 + bcol];

        __syncthreads();
        As[akq + 0][arow] = av.x;
        As[akq + 1][arow] = av.y;
        As[akq + 2][arow] = av.z;
        As[akq + 3][arow] = av.w;
        *(float4*)&Bs[brow][bcol] = bv;
        __syncthreads();

        #pragma unroll
        for (int k = 0; k < BK; ++k) {
            float4 a0 = *(const float4*)&As[k][ty * 8];
            float4 a1 = *(const float4*)&As[k][ty * 8 + 4];
            float4 b0 = *(const float4*)&Bs[k][tx * 8];
            float4 b1 = *(const float4*)&Bs[k][tx * 8 + 4];
            float a_[8] = {a0.x, a0.y, a0.z, a0.w, a1.x, a1.y, a1.z, a1.w};
            float b_[8] = {b0.x, b0.y, b0.z, b0.w, b1.x, b1.y, b1.z, b1.w};
            #pragma unroll
            for (int i = 0; i < 8; ++i)
                #pragma unroll
                for (int j = 0; j < 8; ++j)
                    acc[i][j] = fmaf(a_[i], b_[j], acc[i][j]);
        }
    }

    #pragma unroll
    for (int i = 0; i < 8; ++i) {
        float4 o0 = {acc[i][0], acc[i][1], acc[i][2], acc[i][3]};
        float4 o1 = {acc[i][4], acc[i][5], acc[i][6], acc[i][7]};
        *(float4*)&Cout[(size_t)(m0 + ty * 8 + i) * C_ + n0 + tx * 8]     = o0;
        *(float4*)&Cout[(size_t)(m0 + ty * 8 + i) * C_ + n0 + tx * 8 + 4] = o1;
    }
}

// ---------------------------------------------------------------------------
// RoPE in-place on bf16 [rows, D]; thread handles d = 2j,2j+1 paired with +64.
// ---------------------------------------------------------------------------
__global__ void rope_bf16(__bf16* __restrict__ buf)
{
    const int idx = blockIdx.x * blockDim.x + threadIdx.x;
    const int jj  = idx & 31;          // 32 threads per row
    const int row = idx >> 5;
    const int t   = row & (T_ - 1);
    const int d   = jj * 2;

    const float LOG_THETA = 9.210340371976184f;  // ln(10000)
    const float f1 = (float)t * __expf(-(float)d       * (LOG_THETA / 64.0f));
    const float f2 = (float)t * __expf(-(float)(d + 1) * (LOG_THETA / 64.0f));
    float s1, c1, s2, c2;
    __sincosf(f1, &s1, &c1);
    __sincosf(f2, &s2, &c2);

    __bf16* p = buf + (size_t)row * D_ + d;
    const float x1a = (float)p[0],  x1b = (float)p[1];
    const float x2a = (float)p[64], x2b = (float)p[65];
    p[0]  = (__bf16)(x1a * c1 - x2a * s1);
    p[1]  = (__bf16)(x1b * c2 - x2b * s2);
    p[64] = (__bf16)(x2a * c1 + x1a * s1);
    p[65] = (__bf16)(x2b * c2 + x1b * s2);
}

// ---------------------------------------------------------------------------
// V transpose: vb [BH][T][D] -> vtb [BH][D][T]  (bf16)
// ---------------------------------------------------------------------------
__global__ __launch_bounds__(256)
void transpose_v(const __bf16* __restrict__ vb, __bf16* __restrict__ vtb)
{
    __shared__ __bf16 tl[32][33];
    const int tx = threadIdx.x;        // 0..31
    const int ty = threadIdx.y;        // 0..7
    const int t0 = blockIdx.x * 32;
    const int d0 = blockIdx.y * 32;
    const int bh = blockIdx.z;

    const __bf16* src = vb + ((size_t)bh * T_ + t0) * D_ + d0;
    #pragma unroll
    for (int i = 0; i < 4; ++i) {
        const int tl_row = ty + i * 8;
        tl[tl_row][tx] = src[(size_t)tl_row * D_ + tx];
    }
    __syncthreads();
    __bf16* dst = vtb + ((size_t)bh * D_ + d0) * T_ + t0;
    #pragma unroll
    for (int i = 0; i < 4; ++i) {
        const int dl = ty + i * 8;
        dst[(size_t)dl * T_ + tx] = tl[tx][dl];
    }
}

// ---------------------------------------------------------------------------
// MFMA flash attention (bf16 in, fp32 out). Block = 256 thr = 4 waves.
// QBLK=64 (wave w: rows 16w..16w+15), KBLK=64, causal, GQA.
// mfma_f32_16x16x32_bf16: A row=lane&15, k=(lane>>4)*8+e; C col=lane&15,
// row=(lane>>4)*4+reg.
// ---------------------------------------------------------------------------
#define KS_STRIDE 136   // 64x128 K tile, row stride 136 elems (272 B)
#define PS_STRIDE 72    // 16x64 P tile per wave, row stride 72 elems (144 B)

__global__ __launch_bounds__(256)
void flash_attn_mfma(const __bf16* __restrict__ qb,
                     const __bf16* __restrict__ kb,
                     const __bf16* __restrict__ vtb,
                     float* __restrict__ abuf)
{
    __shared__ __bf16 KsL[64 * KS_STRIDE];        // 17408 B
    __shared__ __bf16 VsL[2 * 128 * 4 * 8];       // 16384 B  [slice][d][octet][8]
    __shared__ __bf16 PsL[4 * 16 * PS_STRIDE];    //  9216 B

    const int tid  = threadIdx.x;
    const int wave = tid >> 6;
    const int lane = tid & 63;
    const int a    = lane & 15;
    const int bq   = lane >> 4;        // 0..3

    const int qti = (int)gridDim.x - 1 - (int)blockIdx.x;   // heavy blocks first
    const int qt0 = qti * 64;
    const int bh  = blockIdx.y;
    const int b   = bh >> 4;
    const int h   = bh & 15;
    const int kvh = h >> 2;

    const __bf16* qg  = qb  + ((size_t)(b * H_ + h) * T_ + qt0 + wave * 16) * D_;
    const __bf16* kg  = kb  + (size_t)(b * HKV_ + kvh) * T_ * D_;
    const __bf16* vtg = vtb + (size_t)(b * HKV_ + kvh) * D_ * T_;

    // Q fragments (held in registers for the whole kernel)
    bf16x8 qf[4];
    #pragma unroll
    for (int ks = 0; ks < 4; ++ks)
        qf[ks] = *(const bf16x8*)&qg[(size_t)a * D_ + ks * 32 + bq * 8];

    f32x4 oacc[8];
    #pragma unroll
    for (int dt = 0; dt < 8; ++dt) oacc[dt] = (f32x4){0.f, 0.f, 0.f, 0.f};
    float m_r[4] = {-INFINITY, -INFINITY, -INFINITY, -INFINITY};
    float l_r[4] = {0.f, 0.f, 0.f, 0.f};

    const float scale = 0.08838834764831845f;   // 1/sqrt(128)
    const int ntiles = qti + 1;

    for (int kt = 0; kt < ntiles; ++kt) {
        const int k0 = kt * 64;
        __syncthreads();   // prior tile's LDS reads complete
        // stage K tile 64x128 (row-major, padded stride)
        #pragma unroll
        for (int i = 0; i < 4; ++i) {
            const int idx = i * 256 + tid;
            const int r = idx >> 4, c8 = (idx & 15) * 8;
            *(bf16x8*)&KsL[r * KS_STRIDE + c8] =
                *(const bf16x8*)&kg[(size_t)(k0 + r) * D_ + c8];
        }
        // stage V^T tile 128x64 into [slice][d][octet][8]
        #pragma unroll
        for (int i = 0; i < 4; ++i) {
            const int idx = i * 256 + tid;
            const int d = idx >> 3, c8 = (idx & 7) * 8;
            const int ss = c8 >> 5, bo = (c8 >> 3) & 3;
            *(bf16x8*)&VsL[ss * 4096 + d * 32 + bo * 8] =
                *(const bf16x8*)&vtg[(size_t)d * T_ + k0 + c8];
        }
        __syncthreads();

        // S = Q K^T  (4 n-tiles of 16 kc, 4 k-slices of 32 d)
        f32x4 sacc[4];
        #pragma unroll
        for (int nt = 0; nt < 4; ++nt) {
            sacc[nt] = (f32x4){0.f, 0.f, 0.f, 0.f};
            #pragma unroll
            for (int ks = 0; ks < 4; ++ks) {
                bf16x8 kf = *(const bf16x8*)&KsL[(nt * 16 + a) * KS_STRIDE + ks * 32 + bq * 8];
                sacc[nt] = mfma16(qf[ks], kf, sacc[nt]);
            }
        }

        // online softmax (rows = bq*4 + r, cols = k0 + nt*16 + a)
        float p[4][4];
        float mrow[4] = {-INFINITY, -INFINITY, -INFINITY, -INFINITY};
        #pragma unroll
        for (int nt = 0; nt < 4; ++nt) {
            const int kc = k0 + nt * 16 + a;
            #pragma unroll
            for (int r = 0; r < 4; ++r) {
                const int qrow = qt0 + wave * 16 + bq * 4 + r;
                float s = sacc[nt][r] * scale;
                s = (kc <= qrow) ? s : -INFINITY;
                p[nt][r] = s;
                mrow[r] = fmaxf(mrow[r], s);
            }
        }
        #pragma unroll
        for (int off = 1; off < 16; off <<= 1)
            #pragma unroll
            for (int r = 0; r < 4; ++r)
                mrow[r] = fmaxf(mrow[r], __shfl_xor(mrow[r], off));

        float corr[4], psum[4];
        #pragma unroll
        for (int r = 0; r < 4; ++r) {
            const float mnew = fmaxf(m_r[r], mrow[r]);
            corr[r] = __expf(m_r[r] - mnew);
            m_r[r] = mnew;
            psum[r] = 0.f;
            #pragma unroll
            for (int nt = 0; nt < 4; ++nt) {
                const float pe = __expf(p[nt][r] - mnew);
                p[nt][r] = pe;
                psum[r] += pe;
            }
        }
        #pragma unroll
        for (int off = 1; off < 16; off <<= 1)
            #pragma unroll
            for (int r = 0; r < 4; ++r)
                psum[r] += __shfl_xor(psum[r], off);
        #pragma unroll
        for (int r = 0; r < 4; ++r) l_r[r] = l_r[r] * corr[r] + psum[r];

        #pragma unroll
        for (int dt = 0; dt < 8; ++dt)
            #pragma unroll
            for (int r = 0; r < 4; ++r) oacc[dt][r] *= corr[r];

        // write P (bf16) to this wave's LDS region
        #pragma unroll
        for (int nt = 0; nt < 4; ++nt)
            #pragma unroll
            for (int r = 0; r < 4; ++r)
                PsL[(wave * 16 + bq * 4 + r) * PS_STRIDE + nt * 16 + a] = (__bf16)p[nt][r];

        // O += P V  (A-frag: row=a, k=kc; B-frag from [slice][d][octet][8])
        bf16x8 pf[2];
        #pragma unroll
        for (int ss = 0; ss < 2; ++ss)
            pf[ss] = *(const bf16x8*)&PsL[(wave * 16 + a) * PS_STRIDE + ss * 32 + bq * 8];
        #pragma unroll
        for (int dt = 0; dt < 8; ++dt) {
            #pragma unroll
            for (int ss = 0; ss < 2; ++ss) {
                bf16x8 vf = *(const bf16x8*)&VsL[ss * 4096 + (dt * 16 + a) * 32 + bq * 8];
                oacc[dt] = mfma16(pf[ss], vf, oacc[dt]);
            }
        }
    }

    // epilogue
    float invl[4];
    #pragma unroll
    for (int r = 0; r < 4; ++r) invl[r] = 1.f / l_r[r];
    #pragma unroll
    for (int dt = 0; dt < 8; ++dt)
        #pragma unroll
        for (int r = 0; r < 4; ++r) {
            const int qrow = qt0 + wave * 16 + bq * 4 + r;
            abuf[((size_t)(b * T_) + qrow) * (H_ * D_) + h * D_ + dt * 16 + a] =
                oacc[dt][r] * invl[r];
        }
}

// ---------------------------------------------------------------------------
extern "C" void kernel_launch(void* const* d_in, const int* in_sizes, int n_in,
                              void* d_out, int out_size, void* d_ws, size_t ws_size,
                              hipStream_t stream)
{
    (void)in_sizes; (void)n_in; (void)out_size; (void)ws_size;
    const float* x  = (const float*)d_in[0];
    const float* Wq = (const float*)d_in[1];
    const float* Wk = (const float*)d_in[2];
    const float* Wv = (const float*)d_in[3];
    const float* Wo = (const float*)d_in[4];
    float* out = (float*)d_out;

    __bf16* qb  = (__bf16*)d_ws;                               // 8.4M elems
    __bf16* kb  = qb + (size_t)B_ * H_   * T_ * D_;
    __bf16* vb  = kb + (size_t)B_ * HKV_ * T_ * D_;
    __bf16* vtb = vb + (size_t)B_ * HKV_ * T_ * D_;
    float* abuf = (float*)(vtb + (size_t)B_ * HKV_ * T_ * D_); // fp32 8.4M

    // 1) fused QKV projection (fp32 math, bf16 out)
    dim3 g1((H_ + 2 * HKV_) * D_ / BN, (B_ * T_) / BM);
    hipLaunchKernelGGL(qkv_gemm, g1, dim3(256), 0, stream,
                       x, Wq, Wk, Wv, qb, kb, vb);

    // 2) RoPE on q and k (bf16 in-place)
    hipLaunchKernelGGL(rope_bf16, dim3(B_ * H_ * T_ * 32 / 256), dim3(256), 0, stream, qb);
    hipLaunchKernelGGL(rope_bf16, dim3(B_ * HKV_ * T_ * 32 / 256), dim3(256), 0, stream, kb);

    // 3) V transpose [BH][T][D] -> [BH][D][T]
    hipLaunchKernelGGL(transpose_v, dim3(T_ / 32, D_ / 32, B_ * HKV_), dim3(32, 8), 0, stream,
                       vb, vtb);

    // 4) MFMA flash attention -> abuf [B, T, H*D] fp32
    hipLaunchKernelGGL(flash_attn_mfma, dim3(T_ / 64, B_ * H_), dim3(256), 0, stream,
                       qb, kb, vtb, abuf);

    // 5) output projection (fp32)
    dim3 g5(C_ / BN, (B_ * T_) / BM);
    hipLaunchKernelGGL(out_gemm, g5, dim3(256), 0, stream, abuf, Wo, out);
}

// Round 4
// 547.361 us; speedup vs baseline: 4.6888x; 2.5940x over previous
//
#include <hip/hip_runtime.h>
#include <math.h>

#define B_ 2
#define T_ 2048
#define C_ 2048
#define H_ 16
#define HKV_ 4
#define D_ 128
#define G_ (H_ / HKV_)
#define GK 2048   // GEMM K dim (== C_)

typedef float f32x4 __attribute__((ext_vector_type(4)));
typedef __bf16 bf16x8 __attribute__((ext_vector_type(8)));

static __device__ __forceinline__ f32x4 mfma16(bf16x8 a, bf16x8 b, f32x4 c) {
    return __builtin_amdgcn_mfma_f32_16x16x32_bf16(a, b, c, 0, 0, 0);
}

// ---------------------------------------------------------------------------
// x fp32 -> bf16, 8 elems/thread
// ---------------------------------------------------------------------------
__global__ __launch_bounds__(256)
void conv_f32_bf16(const float* __restrict__ src, __bf16* __restrict__ dst, int n8)
{
    const int i = blockIdx.x * blockDim.x + threadIdx.x;
    if (i >= n8) return;
    const float4 a = *(const float4*)&src[(size_t)i * 8];
    const float4 b = *(const float4*)&src[(size_t)i * 8 + 4];
    bf16x8 o;
    o[0] = (__bf16)a.x; o[1] = (__bf16)a.y; o[2] = (__bf16)a.z; o[3] = (__bf16)a.w;
    o[4] = (__bf16)b.x; o[5] = (__bf16)b.y; o[6] = (__bf16)b.z; o[7] = (__bf16)b.w;
    *(bf16x8*)&dst[(size_t)i * 8] = o;
}

// ---------------------------------------------------------------------------
// W fp32 [K][N] -> bf16 [N][K]  (transpose + convert), 32x32 LDS tile
// ---------------------------------------------------------------------------
__global__ __launch_bounds__(256)
void tconv(const float* __restrict__ src, __bf16* __restrict__ dst, int N)
{
    __shared__ __bf16 tl[32][34];
    const int tx = threadIdx.x;   // 0..31
    const int ty = threadIdx.y;   // 0..7
    const int k0 = blockIdx.x * 32;
    const int n0 = blockIdx.y * 32;

    #pragma unroll
    for (int i = 0; i < 4; ++i) {
        const int r = ty + i * 8;
        tl[r][tx] = (__bf16)src[(size_t)(k0 + r) * N + n0 + tx];
    }
    __syncthreads();
    #pragma unroll
    for (int i = 0; i < 4; ++i) {
        const int r = ty + i * 8;
        dst[(size_t)(n0 + r) * GK + k0 + tx] = tl[tx][r];
    }
}

// ---------------------------------------------------------------------------
// bf16 MFMA GEMM core: C[128x128 tile] = A[M][K] * Bt[N][K]^T
// 256 thr = 4 waves (2x2), each wave 64x64 = 4x4 frags. BK=64, LDS stride 72.
// Frag mapping (HW-verified via round-3 attention): A row=lane&15,
// k=(lane>>4)*8+e; C row=(lane>>4)*4+reg, col=lane&15.
// ---------------------------------------------------------------------------
#define LSTR 72

#define GEMM_MAIN(At, Bt)                                                       \
    __shared__ __bf16 As[128 * LSTR];                                           \
    __shared__ __bf16 Bs[128 * LSTR];                                           \
    const int tid = threadIdx.x;                                                \
    const int wave = tid >> 6, lane = tid & 63;                                 \
    const int a = lane & 15, bq = lane >> 4;                                    \
    const int wr = wave >> 1, wc = wave & 1;                                    \
    f32x4 acc[4][4];                                                            \
    _Pragma("unroll")                                                           \
    for (int mi = 0; mi < 4; ++mi)                                              \
        _Pragma("unroll")                                                       \
        for (int ni = 0; ni < 4; ++ni) acc[mi][ni] = (f32x4){0.f,0.f,0.f,0.f};  \
    for (int k0 = 0; k0 < GK; k0 += 64) {                                       \
        __syncthreads();                                                        \
        _Pragma("unroll")                                                       \
        for (int i = 0; i < 4; ++i) {                                           \
            const int idx = i * 256 + tid;                                      \
            const int r = idx >> 3, c8 = (idx & 7) * 8;                         \
            *(bf16x8*)&As[r * LSTR + c8] =                                      \
                *(const bf16x8*)&(At)[(size_t)r * GK + k0 + c8];                \
            *(bf16x8*)&Bs[r * LSTR + c8] =                                      \
                *(const bf16x8*)&(Bt)[(size_t)r * GK + k0 + c8];                \
        }                                                                       \
        __syncthreads();                                                        \
        _Pragma("unroll")                                                       \
        for (int ks = 0; ks < 2; ++ks) {                                        \
            bf16x8 af[4], bfr[4];                                               \
            _Pragma("unroll")                                                   \
            for (int mi = 0; mi < 4; ++mi)                                      \
                af[mi] = *(const bf16x8*)&As[(wr*64 + mi*16 + a) * LSTR + ks*32 + bq*8]; \
            _Pragma("unroll")                                                   \
            for (int ni = 0; ni < 4; ++ni)                                      \
                bfr[ni] = *(const bf16x8*)&Bs[(wc*64 + ni*16 + a) * LSTR + ks*32 + bq*8]; \
            _Pragma("unroll")                                                   \
            for (int mi = 0; mi < 4; ++mi)                                      \
                _Pragma("unroll")                                               \
                for (int ni = 0; ni < 4; ++ni)                                  \
                    acc[mi][ni] = mfma16(af[mi], bfr[ni], acc[mi][ni]);         \
        }                                                                       \
    }

// QKV: X[4096][2048]bf16 @ {WqT|WkT|WvT}[N][2048] -> q/k/v [B,NH,T,D] bf16
__global__ __launch_bounds__(256)
void gemm_qkv_mfma(const __bf16* __restrict__ xb,
                   const __bf16* __restrict__ wqt,
                   const __bf16* __restrict__ wkt,
                   const __bf16* __restrict__ wvt,
                   __bf16* __restrict__ qbuf,
                   __bf16* __restrict__ kbuf,
                   __bf16* __restrict__ vbuf)
{
    const int n0 = blockIdx.x * 128;
    const int m0 = blockIdx.y * 128;
    const __bf16* Btp; __bf16* outb; int NH, nloc;
    if (n0 < 2048)      { Btp = wqt + (size_t)n0 * GK;          outb = qbuf; NH = 16; nloc = n0; }
    else if (n0 < 2560) { Btp = wkt + (size_t)(n0 - 2048) * GK; outb = kbuf; NH = 4;  nloc = n0 - 2048; }
    else                { Btp = wvt + (size_t)(n0 - 2560) * GK; outb = vbuf; NH = 4;  nloc = n0 - 2560; }
    const __bf16* Atp = xb + (size_t)m0 * GK;

    GEMM_MAIN(Atp, Btp)

    const int b  = m0 >> 11;       // / T_
    const int t0 = m0 & (T_ - 1);
    const int h0 = nloc >> 7;      // / D_  (tile spans exactly one head)
    __bf16* op = outb + (size_t)(b * NH + h0) * T_ * D_;
    #pragma unroll
    for (int mi = 0; mi < 4; ++mi)
        #pragma unroll
        for (int ni = 0; ni < 4; ++ni)
            #pragma unroll
            for (int rr = 0; rr < 4; ++rr) {
                const int row = t0 + wr * 64 + mi * 16 + bq * 4 + rr;
                const int col = wc * 64 + ni * 16 + a;
                op[(size_t)row * D_ + col] = (__bf16)acc[mi][ni][rr];
            }
}

// OUT: abuf[4096][2048]bf16 @ WoT[2048][2048] -> out fp32 [4096][2048]
__global__ __launch_bounds__(256)
void gemm_out_mfma(const __bf16* __restrict__ ab,
                   const __bf16* __restrict__ wot,
                   float* __restrict__ outp)
{
    const int n0 = blockIdx.x * 128;
    const int m0 = blockIdx.y * 128;
    const __bf16* Atp = ab + (size_t)m0 * GK;
    const __bf16* Btp = wot + (size_t)n0 * GK;

    GEMM_MAIN(Atp, Btp)

    #pragma unroll
    for (int mi = 0; mi < 4; ++mi)
        #pragma unroll
        for (int ni = 0; ni < 4; ++ni)
            #pragma unroll
            for (int rr = 0; rr < 4; ++rr) {
                const int row = m0 + wr * 64 + mi * 16 + bq * 4 + rr;
                const int col = n0 + wc * 64 + ni * 16 + a;
                outp[(size_t)row * C_ + col] = acc[mi][ni][rr];
            }
}

// ---------------------------------------------------------------------------
// RoPE in-place on bf16 [rows, D]
// ---------------------------------------------------------------------------
__global__ void rope_bf16(__bf16* __restrict__ buf)
{
    const int idx = blockIdx.x * blockDim.x + threadIdx.x;
    const int jj  = idx & 31;
    const int row = idx >> 5;
    const int t   = row & (T_ - 1);
    const int d   = jj * 2;

    const float LOG_THETA = 9.210340371976184f;
    const float f1 = (float)t * __expf(-(float)d       * (LOG_THETA / 64.0f));
    const float f2 = (float)t * __expf(-(float)(d + 1) * (LOG_THETA / 64.0f));
    float s1, c1, s2, c2;
    __sincosf(f1, &s1, &c1);
    __sincosf(f2, &s2, &c2);

    __bf16* p = buf + (size_t)row * D_ + d;
    const float x1a = (float)p[0],  x1b = (float)p[1];
    const float x2a = (float)p[64], x2b = (float)p[65];
    p[0]  = (__bf16)(x1a * c1 - x2a * s1);
    p[1]  = (__bf16)(x1b * c2 - x2b * s2);
    p[64] = (__bf16)(x2a * c1 + x1a * s1);
    p[65] = (__bf16)(x2b * c2 + x1b * s2);
}

// ---------------------------------------------------------------------------
// V transpose: vb [BH][T][D] -> vtb [BH][D][T]  (bf16)
// ---------------------------------------------------------------------------
__global__ __launch_bounds__(256)
void transpose_v(const __bf16* __restrict__ vb, __bf16* __restrict__ vtb)
{
    __shared__ __bf16 tl[32][33];
    const int tx = threadIdx.x;
    const int ty = threadIdx.y;
    const int t0 = blockIdx.x * 32;
    const int d0 = blockIdx.y * 32;
    const int bh = blockIdx.z;

    const __bf16* src = vb + ((size_t)bh * T_ + t0) * D_ + d0;
    #pragma unroll
    for (int i = 0; i < 4; ++i) {
        const int r = ty + i * 8;
        tl[r][tx] = src[(size_t)r * D_ + tx];
    }
    __syncthreads();
    __bf16* dst = vtb + ((size_t)bh * D_ + d0) * T_ + t0;
    #pragma unroll
    for (int i = 0; i < 4; ++i) {
        const int dl = ty + i * 8;
        dst[(size_t)dl * T_ + tx] = tl[tx][dl];
    }
}

// ---------------------------------------------------------------------------
// MFMA flash attention (bf16 in, bf16 out). 256 thr = 4 waves, QBLK=64, KBLK=64.
// ---------------------------------------------------------------------------
#define KS_STRIDE 136
#define PS_STRIDE 72

__global__ __launch_bounds__(256)
void flash_attn_mfma(const __bf16* __restrict__ qb,
                     const __bf16* __restrict__ kb,
                     const __bf16* __restrict__ vtb,
                     __bf16* __restrict__ abuf)
{
    __shared__ __bf16 KsL[64 * KS_STRIDE];
    __shared__ __bf16 VsL[2 * 128 * 4 * 8];
    __shared__ __bf16 PsL[4 * 16 * PS_STRIDE];

    const int tid  = threadIdx.x;
    const int wave = tid >> 6;
    const int lane = tid & 63;
    const int a    = lane & 15;
    const int bq   = lane >> 4;

    const int qti = (int)gridDim.x - 1 - (int)blockIdx.x;
    const int qt0 = qti * 64;
    const int bh  = blockIdx.y;
    const int b   = bh >> 4;
    const int h   = bh & 15;
    const int kvh = h >> 2;

    const __bf16* qg  = qb  + ((size_t)(b * H_ + h) * T_ + qt0 + wave * 16) * D_;
    const __bf16* kg  = kb  + (size_t)(b * HKV_ + kvh) * T_ * D_;
    const __bf16* vtg = vtb + (size_t)(b * HKV_ + kvh) * D_ * T_;

    bf16x8 qf[4];
    #pragma unroll
    for (int ks = 0; ks < 4; ++ks)
        qf[ks] = *(const bf16x8*)&qg[(size_t)a * D_ + ks * 32 + bq * 8];

    f32x4 oacc[8];
    #pragma unroll
    for (int dt = 0; dt < 8; ++dt) oacc[dt] = (f32x4){0.f, 0.f, 0.f, 0.f};
    float m_r[4] = {-INFINITY, -INFINITY, -INFINITY, -INFINITY};
    float l_r[4] = {0.f, 0.f, 0.f, 0.f};

    const float scale = 0.08838834764831845f;
    const int ntiles = qti + 1;

    for (int kt = 0; kt < ntiles; ++kt) {
        const int k0 = kt * 64;
        __syncthreads();
        #pragma unroll
        for (int i = 0; i < 4; ++i) {
            const int idx = i * 256 + tid;
            const int r = idx >> 4, c8 = (idx & 15) * 8;
            *(bf16x8*)&KsL[r * KS_STRIDE + c8] =
                *(const bf16x8*)&kg[(size_t)(k0 + r) * D_ + c8];
        }
        #pragma unroll
        for (int i = 0; i < 4; ++i) {
            const int idx = i * 256 + tid;
            const int d = idx >> 3, c8 = (idx & 7) * 8;
            const int ss = c8 >> 5, bo = (c8 >> 3) & 3;
            *(bf16x8*)&VsL[ss * 4096 + d * 32 + bo * 8] =
                *(const bf16x8*)&vtg[(size_t)d * T_ + k0 + c8];
        }
        __syncthreads();

        f32x4 sacc[4];
        #pragma unroll
        for (int nt = 0; nt < 4; ++nt) {
            sacc[nt] = (f32x4){0.f, 0.f, 0.f, 0.f};
            #pragma unroll
            for (int ks = 0; ks < 4; ++ks) {
                bf16x8 kf = *(const bf16x8*)&KsL[(nt * 16 + a) * KS_STRIDE + ks * 32 + bq * 8];
                sacc[nt] = mfma16(qf[ks], kf, sacc[nt]);
            }
        }

        float p[4][4];
        float mrow[4] = {-INFINITY, -INFINITY, -INFINITY, -INFINITY};
        #pragma unroll
        for (int nt = 0; nt < 4; ++nt) {
            const int kc = k0 + nt * 16 + a;
            #pragma unroll
            for (int r = 0; r < 4; ++r) {
                const int qrow = qt0 + wave * 16 + bq * 4 + r;
                float s = sacc[nt][r] * scale;
                s = (kc <= qrow) ? s : -INFINITY;
                p[nt][r] = s;
                mrow[r] = fmaxf(mrow[r], s);
            }
        }
        #pragma unroll
        for (int off = 1; off < 16; off <<= 1)
            #pragma unroll
            for (int r = 0; r < 4; ++r)
                mrow[r] = fmaxf(mrow[r], __shfl_xor(mrow[r], off));

        float corr[4], psum[4];
        #pragma unroll
        for (int r = 0; r < 4; ++r) {
            const float mnew = fmaxf(m_r[r], mrow[r]);
            corr[r] = __expf(m_r[r] - mnew);
            m_r[r] = mnew;
            psum[r] = 0.f;
            #pragma unroll
            for (int nt = 0; nt < 4; ++nt) {
                const float pe = __expf(p[nt][r] - mnew);
                p[nt][r] = pe;
                psum[r] += pe;
            }
        }
        #pragma unroll
        for (int off = 1; off < 16; off <<= 1)
            #pragma unroll
            for (int r = 0; r < 4; ++r)
                psum[r] += __shfl_xor(psum[r], off);
        #pragma unroll
        for (int r = 0; r < 4; ++r) l_r[r] = l_r[r] * corr[r] + psum[r];

        #pragma unroll
        for (int dt = 0; dt < 8; ++dt)
            #pragma unroll
            for (int r = 0; r < 4; ++r) oacc[dt][r] *= corr[r];

        #pragma unroll
        for (int nt = 0; nt < 4; ++nt)
            #pragma unroll
            for (int r = 0; r < 4; ++r)
                PsL[(wave * 16 + bq * 4 + r) * PS_STRIDE + nt * 16 + a] = (__bf16)p[nt][r];

        bf16x8 pf[2];
        #pragma unroll
        for (int ss = 0; ss < 2; ++ss)
            pf[ss] = *(const bf16x8*)&PsL[(wave * 16 + a) * PS_STRIDE + ss * 32 + bq * 8];
        #pragma unroll
        for (int dt = 0; dt < 8; ++dt) {
            #pragma unroll
            for (int ss = 0; ss < 2; ++ss) {
                bf16x8 vf = *(const bf16x8*)&VsL[ss * 4096 + (dt * 16 + a) * 32 + bq * 8];
                oacc[dt] = mfma16(pf[ss], vf, oacc[dt]);
            }
        }
    }

    float invl[4];
    #pragma unroll
    for (int r = 0; r < 4; ++r) invl[r] = 1.f / l_r[r];
    #pragma unroll
    for (int dt = 0; dt < 8; ++dt)
        #pragma unroll
        for (int r = 0; r < 4; ++r) {
            const int qrow = qt0 + wave * 16 + bq * 4 + r;
            abuf[((size_t)(b * T_) + qrow) * (H_ * D_) + h * D_ + dt * 16 + a] =
                (__bf16)(oacc[dt][r] * invl[r]);
        }
}

// ---------------------------------------------------------------------------
extern "C" void kernel_launch(void* const* d_in, const int* in_sizes, int n_in,
                              void* d_out, int out_size, void* d_ws, size_t ws_size,
                              hipStream_t stream)
{
    (void)in_sizes; (void)n_in; (void)out_size; (void)ws_size;
    const float* x  = (const float*)d_in[0];
    const float* Wq = (const float*)d_in[1];
    const float* Wk = (const float*)d_in[2];
    const float* Wv = (const float*)d_in[3];
    const float* Wo = (const float*)d_in[4];
    float* out = (float*)d_out;

    __bf16* xb  = (__bf16*)d_ws;                      // 4096*2048
    __bf16* wqt = xb  + (size_t)4096 * 2048;          // 2048*2048
    __bf16* wkt = wqt + (size_t)2048 * 2048;          // 512*2048
    __bf16* wvt = wkt + (size_t)512 * 2048;           // 512*2048
    __bf16* wot = wvt + (size_t)512 * 2048;           // 2048*2048
    __bf16* qb  = wot + (size_t)2048 * 2048;          // B*H*T*D
    __bf16* kb  = qb  + (size_t)B_ * H_   * T_ * D_;
    __bf16* vb  = kb  + (size_t)B_ * HKV_ * T_ * D_;
    __bf16* vtb = vb  + (size_t)B_ * HKV_ * T_ * D_;
    __bf16* ab  = vtb + (size_t)B_ * HKV_ * T_ * D_;  // B*T*H*D bf16

    // 0) converts
    hipLaunchKernelGGL(conv_f32_bf16, dim3(4096), dim3(256), 0, stream,
                       x, xb, (int)((size_t)B_ * T_ * C_ / 8));
    hipLaunchKernelGGL(tconv, dim3(64, 64), dim3(32, 8), 0, stream, Wq, wqt, 2048);
    hipLaunchKernelGGL(tconv, dim3(64, 16), dim3(32, 8), 0, stream, Wk, wkt, 512);
    hipLaunchKernelGGL(tconv, dim3(64, 16), dim3(32, 8), 0, stream, Wv, wvt, 512);
    hipLaunchKernelGGL(tconv, dim3(64, 64), dim3(32, 8), 0, stream, Wo, wot, 2048);

    // 1) QKV projection (bf16 MFMA)
    hipLaunchKernelGGL(gemm_qkv_mfma, dim3(24, 32), dim3(256), 0, stream,
                       xb, wqt, wkt, wvt, qb, kb, vb);

    // 2) RoPE on q and k
    hipLaunchKernelGGL(rope_bf16, dim3(B_ * H_ * T_ * 32 / 256), dim3(256), 0, stream, qb);
    hipLaunchKernelGGL(rope_bf16, dim3(B_ * HKV_ * T_ * 32 / 256), dim3(256), 0, stream, kb);

    // 3) V transpose
    hipLaunchKernelGGL(transpose_v, dim3(T_ / 32, D_ / 32, B_ * HKV_), dim3(32, 8), 0, stream,
                       vb, vtb);

    // 4) flash attention -> ab (bf16)
    hipLaunchKernelGGL(flash_attn_mfma, dim3(T_ / 64, B_ * H_), dim3(256), 0, stream,
                       qb, kb, vtb, ab);

    // 5) output projection (bf16 MFMA, fp32 out)
    hipLaunchKernelGGL(gemm_out_mfma, dim3(16, 32), dim3(256), 0, stream,
                       ab, wot, out);
}

// Round 5
// 374.293 us; speedup vs baseline: 6.8568x; 1.4624x over previous
//
#include <hip/hip_runtime.h>
#include <math.h>

#define B_ 2
#define T_ 2048
#define C_ 2048
#define H_ 16
#define HKV_ 4
#define D_ 128
#define G_ (H_ / HKV_)
#define GK 2048   // GEMM K dim (== C_)

typedef float f32x4 __attribute__((ext_vector_type(4)));
typedef __bf16 bf16x8 __attribute__((ext_vector_type(8)));

static __device__ __forceinline__ f32x4 mfma16(bf16x8 a, bf16x8 b, f32x4 c) {
    return __builtin_amdgcn_mfma_f32_16x16x32_bf16(a, b, c, 0, 0, 0);
}

// ---------------------------------------------------------------------------
// x fp32 -> bf16, 8 elems/thread
// ---------------------------------------------------------------------------
__global__ __launch_bounds__(256)
void conv_f32_bf16(const float* __restrict__ src, __bf16* __restrict__ dst, int n8)
{
    const int i = blockIdx.x * blockDim.x + threadIdx.x;
    if (i >= n8) return;
    const float4 a = *(const float4*)&src[(size_t)i * 8];
    const float4 b = *(const float4*)&src[(size_t)i * 8 + 4];
    bf16x8 o;
    o[0] = (__bf16)a.x; o[1] = (__bf16)a.y; o[2] = (__bf16)a.z; o[3] = (__bf16)a.w;
    o[4] = (__bf16)b.x; o[5] = (__bf16)b.y; o[6] = (__bf16)b.z; o[7] = (__bf16)b.w;
    *(bf16x8*)&dst[(size_t)i * 8] = o;
}

// ---------------------------------------------------------------------------
// W fp32 [K][N] -> bf16 [N][K]  (transpose + convert), 32x32 LDS tile
// ---------------------------------------------------------------------------
__global__ __launch_bounds__(256)
void tconv(const float* __restrict__ src, __bf16* __restrict__ dst, int N)
{
    __shared__ __bf16 tl[32][34];
    const int tx = threadIdx.x;   // 0..31
    const int ty = threadIdx.y;   // 0..7
    const int k0 = blockIdx.x * 32;
    const int n0 = blockIdx.y * 32;

    #pragma unroll
    for (int i = 0; i < 4; ++i) {
        const int r = ty + i * 8;
        tl[r][tx] = (__bf16)src[(size_t)(k0 + r) * N + n0 + tx];
    }
    __syncthreads();
    #pragma unroll
    for (int i = 0; i < 4; ++i) {
        const int r = ty + i * 8;
        dst[(size_t)(n0 + r) * GK + k0 + tx] = tl[tx][r];
    }
}

// ---------------------------------------------------------------------------
// bf16 MFMA GEMM core: C[128x128 tile] = A[M][K] * Bt[N][K]^T
// 256 thr = 4 waves (2x2), each wave 64x64 = 4x4 frags. BK=64, LDS stride 72.
// ---------------------------------------------------------------------------
#define LSTR 72

#define GEMM_MAIN(At, Bt)                                                       \
    __shared__ __bf16 As[128 * LSTR];                                           \
    __shared__ __bf16 Bs[128 * LSTR];                                           \
    const int tid = threadIdx.x;                                                \
    const int wave = tid >> 6, lane = tid & 63;                                 \
    const int a = lane & 15, bq = lane >> 4;                                    \
    const int wr = wave >> 1, wc = wave & 1;                                    \
    f32x4 acc[4][4];                                                            \
    _Pragma("unroll")                                                           \
    for (int mi = 0; mi < 4; ++mi)                                              \
        _Pragma("unroll")                                                       \
        for (int ni = 0; ni < 4; ++ni) acc[mi][ni] = (f32x4){0.f,0.f,0.f,0.f};  \
    for (int k0 = 0; k0 < GK; k0 += 64) {                                       \
        __syncthreads();                                                        \
        _Pragma("unroll")                                                       \
        for (int i = 0; i < 4; ++i) {                                           \
            const int idx = i * 256 + tid;                                      \
            const int r = idx >> 3, c8 = (idx & 7) * 8;                         \
            *(bf16x8*)&As[r * LSTR + c8] =                                      \
                *(const bf16x8*)&(At)[(size_t)r * GK + k0 + c8];                \
            *(bf16x8*)&Bs[r * LSTR + c8] =                                      \
                *(const bf16x8*)&(Bt)[(size_t)r * GK + k0 + c8];                \
        }                                                                       \
        __syncthreads();                                                        \
        _Pragma("unroll")                                                       \
        for (int ks = 0; ks < 2; ++ks) {                                        \
            bf16x8 af[4], bfr[4];                                               \
            _Pragma("unroll")                                                   \
            for (int mi = 0; mi < 4; ++mi)                                      \
                af[mi] = *(const bf16x8*)&As[(wr*64 + mi*16 + a) * LSTR + ks*32 + bq*8]; \
            _Pragma("unroll")                                                   \
            for (int ni = 0; ni < 4; ++ni)                                      \
                bfr[ni] = *(const bf16x8*)&Bs[(wc*64 + ni*16 + a) * LSTR + ks*32 + bq*8]; \
            _Pragma("unroll")                                                   \
            for (int mi = 0; mi < 4; ++mi)                                      \
                _Pragma("unroll")                                               \
                for (int ni = 0; ni < 4; ++ni)                                  \
                    acc[mi][ni] = mfma16(af[mi], bfr[ni], acc[mi][ni]);         \
        }                                                                       \
    }

// QKV: X[4096][2048]bf16 @ {WqT|WkT|WvT}[N][2048] -> q/k/v [B,NH,T,D] bf16
__global__ __launch_bounds__(256)
void gemm_qkv_mfma(const __bf16* __restrict__ xb,
                   const __bf16* __restrict__ wqt,
                   const __bf16* __restrict__ wkt,
                   const __bf16* __restrict__ wvt,
                   __bf16* __restrict__ qbuf,
                   __bf16* __restrict__ kbuf,
                   __bf16* __restrict__ vbuf)
{
    const int n0 = blockIdx.x * 128;
    const int m0 = blockIdx.y * 128;
    const __bf16* Btp; __bf16* outb; int NH, nloc;
    if (n0 < 2048)      { Btp = wqt + (size_t)n0 * GK;          outb = qbuf; NH = 16; nloc = n0; }
    else if (n0 < 2560) { Btp = wkt + (size_t)(n0 - 2048) * GK; outb = kbuf; NH = 4;  nloc = n0 - 2048; }
    else                { Btp = wvt + (size_t)(n0 - 2560) * GK; outb = vbuf; NH = 4;  nloc = n0 - 2560; }
    const __bf16* Atp = xb + (size_t)m0 * GK;

    GEMM_MAIN(Atp, Btp)

    const int b  = m0 >> 11;
    const int t0 = m0 & (T_ - 1);
    const int h0 = nloc >> 7;
    __bf16* op = outb + (size_t)(b * NH + h0) * T_ * D_;
    #pragma unroll
    for (int mi = 0; mi < 4; ++mi)
        #pragma unroll
        for (int ni = 0; ni < 4; ++ni)
            #pragma unroll
            for (int rr = 0; rr < 4; ++rr) {
                const int row = t0 + wr * 64 + mi * 16 + bq * 4 + rr;
                const int col = wc * 64 + ni * 16 + a;
                op[(size_t)row * D_ + col] = (__bf16)acc[mi][ni][rr];
            }
}

// OUT: abuf[4096][2048]bf16 @ WoT[2048][2048] -> out fp32 [4096][2048]
__global__ __launch_bounds__(256)
void gemm_out_mfma(const __bf16* __restrict__ ab,
                   const __bf16* __restrict__ wot,
                   float* __restrict__ outp)
{
    const int n0 = blockIdx.x * 128;
    const int m0 = blockIdx.y * 128;
    const __bf16* Atp = ab + (size_t)m0 * GK;
    const __bf16* Btp = wot + (size_t)n0 * GK;

    GEMM_MAIN(Atp, Btp)

    #pragma unroll
    for (int mi = 0; mi < 4; ++mi)
        #pragma unroll
        for (int ni = 0; ni < 4; ++ni)
            #pragma unroll
            for (int rr = 0; rr < 4; ++rr) {
                const int row = m0 + wr * 64 + mi * 16 + bq * 4 + rr;
                const int col = n0 + wc * 64 + ni * 16 + a;
                outp[(size_t)row * C_ + col] = acc[mi][ni][rr];
            }
}

// ---------------------------------------------------------------------------
// RoPE in-place on bf16 [rows, D]
// ---------------------------------------------------------------------------
__global__ void rope_bf16(__bf16* __restrict__ buf)
{
    const int idx = blockIdx.x * blockDim.x + threadIdx.x;
    const int jj  = idx & 31;
    const int row = idx >> 5;
    const int t   = row & (T_ - 1);
    const int d   = jj * 2;

    const float LOG_THETA = 9.210340371976184f;
    const float f1 = (float)t * __expf(-(float)d       * (LOG_THETA / 64.0f));
    const float f2 = (float)t * __expf(-(float)(d + 1) * (LOG_THETA / 64.0f));
    float s1, c1, s2, c2;
    __sincosf(f1, &s1, &c1);
    __sincosf(f2, &s2, &c2);

    __bf16* p = buf + (size_t)row * D_ + d;
    const float x1a = (float)p[0],  x1b = (float)p[1];
    const float x2a = (float)p[64], x2b = (float)p[65];
    p[0]  = (__bf16)(x1a * c1 - x2a * s1);
    p[1]  = (__bf16)(x1b * c2 - x2b * s2);
    p[64] = (__bf16)(x2a * c1 + x1a * s1);
    p[65] = (__bf16)(x2b * c2 + x1b * s2);
}

// ---------------------------------------------------------------------------
// V transpose: vb [BH][T][D] -> vtb [BH][D][T]  (bf16)
// ---------------------------------------------------------------------------
__global__ __launch_bounds__(256)
void transpose_v(const __bf16* __restrict__ vb, __bf16* __restrict__ vtb)
{
    __shared__ __bf16 tl[32][33];
    const int tx = threadIdx.x;
    const int ty = threadIdx.y;
    const int t0 = blockIdx.x * 32;
    const int d0 = blockIdx.y * 32;
    const int bh = blockIdx.z;

    const __bf16* src = vb + ((size_t)bh * T_ + t0) * D_ + d0;
    #pragma unroll
    for (int i = 0; i < 4; ++i) {
        const int r = ty + i * 8;
        tl[r][tx] = src[(size_t)r * D_ + tx];
    }
    __syncthreads();
    __bf16* dst = vtb + ((size_t)bh * D_ + d0) * T_ + t0;
    #pragma unroll
    for (int i = 0; i < 4; ++i) {
        const int dl = ty + i * 8;
        dst[(size_t)dl * T_ + tx] = tl[tx][dl];
    }
}

// ---------------------------------------------------------------------------
// MFMA flash attention v2 (bf16 in, bf16 out). 512 thr = 8 waves.
// QBLK=128 (wave w: rows 16w..16w+15), KBLK=64, causal, GQA.
// Causal pairing: block p handles q-tiles (15-p) then (p) -> 34 K-iters each,
// grid = 8 pairs x 32 bh = 256 blocks (1/CU, 2 waves/SIMD).
// Async-stage: next tile's K/V global->reg loads issue before compute,
// LDS writes land after the post-compute barrier (T14).
// ---------------------------------------------------------------------------
#define KS_STRIDE 136   // K tile row stride (elems): 272 B
#define PS_STRIDE 76    // P tile row stride (elems): 152 B (conflict-free scatter)

__global__ __launch_bounds__(512)
void flash_attn_mfma(const __bf16* __restrict__ qb,
                     const __bf16* __restrict__ kb,
                     const __bf16* __restrict__ vtb,
                     __bf16* __restrict__ abuf)
{
    __shared__ __bf16 KsL[64 * KS_STRIDE];        // 17408 B
    __shared__ __bf16 VsL[2 * 128 * 4 * 8];       // 16384 B  [slice][d][octet][8]
    __shared__ __bf16 PsL[8 * 16 * PS_STRIDE];    // 19456 B

    const int tid  = threadIdx.x;
    const int wave = tid >> 6;
    const int lane = tid & 63;
    const int a    = lane & 15;
    const int bq   = lane >> 4;

    const int pair = blockIdx.x;           // 0..7
    const int bh   = blockIdx.y;
    const int b    = bh >> 4;
    const int h    = bh & 15;
    const int kvh  = h >> 2;

    const __bf16* kg  = kb  + (size_t)(b * HKV_ + kvh) * T_ * D_;
    const __bf16* vtg = vtb + (size_t)(b * HKV_ + kvh) * D_ * T_;

    const float scale = 0.08838834764831845f;   // 1/sqrt(128)

    for (int half = 0; half < 2; ++half) {
        const int qti = half == 0 ? (15 - pair) : pair;
        const int qt0 = qti * 128;
        const int ntiles = 2 * qti + 2;

        const __bf16* qg = qb + ((size_t)(b * H_ + h) * T_ + qt0 + wave * 16) * D_;
        bf16x8 qf[4];
        #pragma unroll
        for (int ks = 0; ks < 4; ++ks)
            qf[ks] = *(const bf16x8*)&qg[(size_t)a * D_ + ks * 32 + bq * 8];

        f32x4 oacc[8];
        #pragma unroll
        for (int dt = 0; dt < 8; ++dt) oacc[dt] = (f32x4){0.f, 0.f, 0.f, 0.f};
        float m_r[4] = {-INFINITY, -INFINITY, -INFINITY, -INFINITY};
        float l_r[4] = {0.f, 0.f, 0.f, 0.f};

        bf16x8 kpre[2], vpre[2];
        // prologue: stage tile 0
        #pragma unroll
        for (int it = 0; it < 2; ++it) {
            const int idx = it * 512 + tid;
            const int r = idx >> 4, c8 = (idx & 15) * 8;
            kpre[it] = *(const bf16x8*)&kg[(size_t)r * D_ + c8];
            const int bo = idx & 3, dd = (idx >> 2) & 127, ss2 = idx >> 9;
            vpre[it] = *(const bf16x8*)&vtg[(size_t)dd * T_ + ss2 * 32 + bo * 8];
        }
        __syncthreads();   // prior half's LDS reads complete
        #pragma unroll
        for (int it = 0; it < 2; ++it) {
            const int idx = it * 512 + tid;
            const int r = idx >> 4, c8 = (idx & 15) * 8;
            *(bf16x8*)&KsL[r * KS_STRIDE + c8] = kpre[it];
            *(bf16x8*)&VsL[idx * 8] = vpre[it];
        }
        __syncthreads();

        for (int kt = 0; kt < ntiles; ++kt) {
            const int k0 = kt * 64;
            // issue next tile's global loads (latency hides under compute)
            if (kt + 1 < ntiles) {
                const int k0n = k0 + 64;
                #pragma unroll
                for (int it = 0; it < 2; ++it) {
                    const int idx = it * 512 + tid;
                    const int r = idx >> 4, c8 = (idx & 15) * 8;
                    kpre[it] = *(const bf16x8*)&kg[(size_t)(k0n + r) * D_ + c8];
                    const int bo = idx & 3, dd = (idx >> 2) & 127, ss2 = idx >> 9;
                    vpre[it] = *(const bf16x8*)&vtg[(size_t)dd * T_ + k0n + ss2 * 32 + bo * 8];
                }
            }

            // S = Q K^T
            f32x4 sacc[4];
            #pragma unroll
            for (int nt = 0; nt < 4; ++nt) {
                sacc[nt] = (f32x4){0.f, 0.f, 0.f, 0.f};
                #pragma unroll
                for (int ks = 0; ks < 4; ++ks) {
                    bf16x8 kf = *(const bf16x8*)&KsL[(nt * 16 + a) * KS_STRIDE + ks * 32 + bq * 8];
                    sacc[nt] = mfma16(qf[ks], kf, sacc[nt]);
                }
            }

            // online softmax (rows = bq*4 + r, cols = k0 + nt*16 + a)
            float p[4][4];
            float mrow[4] = {-INFINITY, -INFINITY, -INFINITY, -INFINITY};
            #pragma unroll
            for (int nt = 0; nt < 4; ++nt) {
                const int kc = k0 + nt * 16 + a;
                #pragma unroll
                for (int r = 0; r < 4; ++r) {
                    const int qrow = qt0 + wave * 16 + bq * 4 + r;
                    float s = sacc[nt][r] * scale;
                    s = (kc <= qrow) ? s : -INFINITY;
                    p[nt][r] = s;
                    mrow[r] = fmaxf(mrow[r], s);
                }
            }
            #pragma unroll
            for (int off = 1; off < 16; off <<= 1)
                #pragma unroll
                for (int r = 0; r < 4; ++r)
                    mrow[r] = fmaxf(mrow[r], __shfl_xor(mrow[r], off));

            float corr[4], psum[4];
            #pragma unroll
            for (int r = 0; r < 4; ++r) {
                const float mnew = fmaxf(m_r[r], mrow[r]);
                corr[r] = __expf(m_r[r] - mnew);
                m_r[r] = mnew;
                psum[r] = 0.f;
                #pragma unroll
                for (int nt = 0; nt < 4; ++nt) {
                    const float pe = __expf(p[nt][r] - mnew);
                    p[nt][r] = pe;
                    psum[r] += pe;
                }
            }
            #pragma unroll
            for (int off = 1; off < 16; off <<= 1)
                #pragma unroll
                for (int r = 0; r < 4; ++r)
                    psum[r] += __shfl_xor(psum[r], off);
            #pragma unroll
            for (int r = 0; r < 4; ++r) l_r[r] = l_r[r] * corr[r] + psum[r];

            #pragma unroll
            for (int dt = 0; dt < 8; ++dt)
                #pragma unroll
                for (int r = 0; r < 4; ++r) oacc[dt][r] *= corr[r];

            // write P (bf16) to this wave's LDS region
            #pragma unroll
            for (int nt = 0; nt < 4; ++nt)
                #pragma unroll
                for (int r = 0; r < 4; ++r)
                    PsL[(wave * 16 + bq * 4 + r) * PS_STRIDE + nt * 16 + a] = (__bf16)p[nt][r];

            // O += P V
            bf16x8 pf[2];
            #pragma unroll
            for (int ss = 0; ss < 2; ++ss)
                pf[ss] = *(const bf16x8*)&PsL[(wave * 16 + a) * PS_STRIDE + ss * 32 + bq * 8];
            #pragma unroll
            for (int dt = 0; dt < 8; ++dt) {
                #pragma unroll
                for (int ss = 0; ss < 2; ++ss) {
                    bf16x8 vf = *(const bf16x8*)&VsL[ss * 4096 + (dt * 16 + a) * 32 + bq * 8];
                    oacc[dt] = mfma16(pf[ss], vf, oacc[dt]);
                }
            }

            __syncthreads();   // all waves done reading K/V for this tile
            if (kt + 1 < ntiles) {
                #pragma unroll
                for (int it = 0; it < 2; ++it) {
                    const int idx = it * 512 + tid;
                    const int r = idx >> 4, c8 = (idx & 15) * 8;
                    *(bf16x8*)&KsL[r * KS_STRIDE + c8] = kpre[it];
                    *(bf16x8*)&VsL[idx * 8] = vpre[it];
                }
                __syncthreads();
            }
        }

        // epilogue
        float invl[4];
        #pragma unroll
        for (int r = 0; r < 4; ++r) invl[r] = 1.f / l_r[r];
        #pragma unroll
        for (int dt = 0; dt < 8; ++dt)
            #pragma unroll
            for (int r = 0; r < 4; ++r) {
                const int qrow = qt0 + wave * 16 + bq * 4 + r;
                abuf[((size_t)(b * T_) + qrow) * (H_ * D_) + h * D_ + dt * 16 + a] =
                    (__bf16)(oacc[dt][r] * invl[r]);
            }
    }
}

// ---------------------------------------------------------------------------
extern "C" void kernel_launch(void* const* d_in, const int* in_sizes, int n_in,
                              void* d_out, int out_size, void* d_ws, size_t ws_size,
                              hipStream_t stream)
{
    (void)in_sizes; (void)n_in; (void)out_size; (void)ws_size;
    const float* x  = (const float*)d_in[0];
    const float* Wq = (const float*)d_in[1];
    const float* Wk = (const float*)d_in[2];
    const float* Wv = (const float*)d_in[3];
    const float* Wo = (const float*)d_in[4];
    float* out = (float*)d_out;

    __bf16* xb  = (__bf16*)d_ws;                      // 4096*2048
    __bf16* wqt = xb  + (size_t)4096 * 2048;          // 2048*2048
    __bf16* wkt = wqt + (size_t)2048 * 2048;          // 512*2048
    __bf16* wvt = wkt + (size_t)512 * 2048;           // 512*2048
    __bf16* wot = wvt + (size_t)512 * 2048;           // 2048*2048
    __bf16* qb  = wot + (size_t)2048 * 2048;          // B*H*T*D
    __bf16* kb  = qb  + (size_t)B_ * H_   * T_ * D_;
    __bf16* vb  = kb  + (size_t)B_ * HKV_ * T_ * D_;
    __bf16* vtb = vb  + (size_t)B_ * HKV_ * T_ * D_;
    __bf16* ab  = vtb + (size_t)B_ * HKV_ * T_ * D_;  // B*T*H*D bf16

    // 0) converts
    hipLaunchKernelGGL(conv_f32_bf16, dim3(4096), dim3(256), 0, stream,
                       x, xb, (int)((size_t)B_ * T_ * C_ / 8));
    hipLaunchKernelGGL(tconv, dim3(64, 64), dim3(32, 8), 0, stream, Wq, wqt, 2048);
    hipLaunchKernelGGL(tconv, dim3(64, 16), dim3(32, 8), 0, stream, Wk, wkt, 512);
    hipLaunchKernelGGL(tconv, dim3(64, 16), dim3(32, 8), 0, stream, Wv, wvt, 512);
    hipLaunchKernelGGL(tconv, dim3(64, 64), dim3(32, 8), 0, stream, Wo, wot, 2048);

    // 1) QKV projection (bf16 MFMA)
    hipLaunchKernelGGL(gemm_qkv_mfma, dim3(24, 32), dim3(256), 0, stream,
                       xb, wqt, wkt, wvt, qb, kb, vb);

    // 2) RoPE on q and k
    hipLaunchKernelGGL(rope_bf16, dim3(B_ * H_ * T_ * 32 / 256), dim3(256), 0, stream, qb);
    hipLaunchKernelGGL(rope_bf16, dim3(B_ * HKV_ * T_ * 32 / 256), dim3(256), 0, stream, kb);

    // 3) V transpose
    hipLaunchKernelGGL(transpose_v, dim3(T_ / 32, D_ / 32, B_ * HKV_), dim3(32, 8), 0, stream,
                       vb, vtb);

    // 4) flash attention v2 -> ab (bf16)
    hipLaunchKernelGGL(flash_attn_mfma, dim3(8, B_ * H_), dim3(512), 0, stream,
                       qb, kb, vtb, ab);

    // 5) output projection (bf16 MFMA, fp32 out)
    hipLaunchKernelGGL(gemm_out_mfma, dim3(16, 32), dim3(256), 0, stream,
                       ab, wot, out);
}